// Round 9
// baseline (312.512 us; speedup 1.0000x reference)
//
#include <hip/hip_runtime.h>
#include <math.h>

typedef __attribute__((ext_vector_type(8))) short short8;
typedef __attribute__((ext_vector_type(4))) float f32x4;

#define UNITS 512
#define DIN 128

// ws float offsets:
#define WS_COLSA  0        // 8 slots x 128, colsum(A), atomic (zeroed)
#define WS_SCALE  1024     // 512
#define WS_SHIFT  1536     // 512
#define WS_ESLOT  2048     // 512 entropy slots, atomic (zeroed)
#define WS_GF     2560     // 16384, G final (128x128)
#define WS_WHI    19456    // 65536 ushorts (32768 floats)
#define WS_WLO    52224    // 65536 ushorts
#define N_ESLOT   512
#define WS_ZERO_FLOATS 2560

#define GRAM_BLOCKS 512    // G partials: GRAM_BLOCKS x 16384 floats in d_out scratch
#define CAP 128            // candidate-list capacity per row (overflow -> fallback)

__device__ __forceinline__ unsigned short f2bf(float f) {
    unsigned u = __float_as_uint(f);
    unsigned r = (u + 0x7FFFu + ((u >> 16) & 1u)) >> 16;   // RNE
    return (unsigned short)r;
}
__device__ __forceinline__ float bf2f(unsigned short h) {
    return __uint_as_float(((unsigned)h) << 16);
}

// K1a: Gram partials G_b = A_b^T A_b (3-term split-bf16 MFMA) + colsum(A).
__global__ __launch_bounds__(256) void k1a_gram(const float* __restrict__ A,
                                                float* __restrict__ Gpart,
                                                float* __restrict__ ws, int Brows)
{
    __shared__ float As[32][133];
    __shared__ float s_lds[128];
    const int t = threadIdx.x;
    const int wave = t >> 6, lane = t & 63, lg = lane >> 4, lm = lane & 15;
    const int rowsPerBlk = Brows / GRAM_BLOCKS;   // 256
    const int r0 = blockIdx.x * rowsPerBlk;

    if (t < 128) s_lds[t] = 0.f;
    float s_part[4] = {0.f, 0.f, 0.f, 0.f};

    f32x4 acc[16];
#pragma unroll
    for (int i = 0; i < 16; ++i) acc[i] = (f32x4){0.f, 0.f, 0.f, 0.f};

    for (int kk = 0; kk < rowsPerBlk; kk += 32) {
        __syncthreads();
#pragma unroll
        for (int i = 0; i < 4; ++i) {
            int fi = t + i * 256;
            int row = fi >> 5, c4 = (fi & 31) * 4;
            float4 v = *(const float4*)(A + (size_t)(r0 + kk + row) * DIN + c4);
            *(float4*)&As[row][c4] = v;
            s_part[0] += v.x; s_part[1] += v.y; s_part[2] += v.z; s_part[3] += v.w;
        }
        __syncthreads();

        short8 fh[8], fl[8];
#pragma unroll
        for (int f = 0; f < 8; ++f) {
#pragma unroll
            for (int j = 0; j < 8; ++j) {
                float v = As[lg * 8 + j][f * 16 + lm];
                unsigned uv = __float_as_uint(v);
                float lo = v - __uint_as_float(uv & 0xFFFF0000u);
                fh[f][j] = (short)(uv >> 16);
                fl[f][j] = (short)(__float_as_uint(lo) >> 16);
            }
        }
        short8 ah0, al0, ah1, al1;
#pragma unroll
        for (int j = 0; j < 8; ++j) {
            float v0 = As[lg * 8 + j][wave * 32 + lm];
            float v1 = As[lg * 8 + j][wave * 32 + 16 + lm];
            unsigned u0 = __float_as_uint(v0), u1 = __float_as_uint(v1);
            float l0 = v0 - __uint_as_float(u0 & 0xFFFF0000u);
            float l1 = v1 - __uint_as_float(u1 & 0xFFFF0000u);
            ah0[j] = (short)(u0 >> 16);
            al0[j] = (short)(__float_as_uint(l0) >> 16);
            ah1[j] = (short)(u1 >> 16);
            al1[j] = (short)(__float_as_uint(l1) >> 16);
        }

#pragma unroll
        for (int tj = 0; tj < 8; ++tj) {
            acc[tj]     = __builtin_amdgcn_mfma_f32_16x16x32_bf16(al0, fh[tj], acc[tj], 0, 0, 0);
            acc[tj]     = __builtin_amdgcn_mfma_f32_16x16x32_bf16(ah0, fl[tj], acc[tj], 0, 0, 0);
            acc[tj]     = __builtin_amdgcn_mfma_f32_16x16x32_bf16(ah0, fh[tj], acc[tj], 0, 0, 0);
            acc[8 + tj] = __builtin_amdgcn_mfma_f32_16x16x32_bf16(al1, fh[tj], acc[8 + tj], 0, 0, 0);
            acc[8 + tj] = __builtin_amdgcn_mfma_f32_16x16x32_bf16(ah1, fl[tj], acc[8 + tj], 0, 0, 0);
            acc[8 + tj] = __builtin_amdgcn_mfma_f32_16x16x32_bf16(ah1, fh[tj], acc[8 + tj], 0, 0, 0);
        }
    }

#pragma unroll
    for (int j = 0; j < 4; ++j) atomicAdd(&s_lds[(t & 31) * 4 + j], s_part[j]);
    __syncthreads();
    if (t < 128) atomicAdd(ws + WS_COLSA + (blockIdx.x & 7) * 128 + t, s_lds[t]);

    float* Gs = Gpart + (size_t)blockIdx.x * 16384;
#pragma unroll
    for (int a2 = 0; a2 < 2; ++a2) {
#pragma unroll
        for (int tj = 0; tj < 8; ++tj) {
#pragma unroll
            for (int g = 0; g < 4; ++g) {
                int gi = (2 * wave + a2) * 16 + lg * 4 + g;
                int gj = tj * 16 + lm;
                Gs[gi * 128 + gj] = acc[a2 * 8 + tj][g];
            }
        }
    }
}

// K1b: reduce GRAM_BLOCKS partials -> G final in ws
__global__ __launch_bounds__(256) void k1b_sumG(const float* __restrict__ Gpart,
                                                float* __restrict__ ws)
{
    int i = blockIdx.x * 256 + threadIdx.x;   // 0..16383
    float v = 0.f;
#pragma unroll 8
    for (int s = 0; s < GRAM_BLOCKS; ++s) v += Gpart[(size_t)s * 16384 + i];
    ws[WS_GF + i] = v;
}

// K2: per-column BN stats from Gram: mean = (colsum(A).w)/N, sumsq = w^T G w.
__global__ __launch_bounds__(128) void k2_finalize(
    const float* __restrict__ W, const float* __restrict__ gamma,
    const float* __restrict__ beta, float* __restrict__ ws, int Brows)
{
    __shared__ float wcol[128];
    __shared__ float red[4];
    const int t = threadIdx.x, n = blockIdx.x;
    wcol[t] = W[(size_t)t * UNITS + n];
    __syncthreads();
    const float* GF = ws + WS_GF;
    float q = 0.f;
#pragma unroll 8
    for (int i = 0; i < 128; ++i) q += GF[i * 128 + t] * wcol[i];
    q *= wcol[t];
    float csa = 0.f;
#pragma unroll
    for (int sl = 0; sl < 8; ++sl) csa += ws[WS_COLSA + sl * 128 + t];
    float mp = csa * wcol[t];
#pragma unroll
    for (int off = 32; off; off >>= 1) {
        q  += __shfl_xor(q, off, 64);
        mp += __shfl_xor(mp, off, 64);
    }
    if ((t & 63) == 0) { red[(t >> 6) * 2] = q; red[(t >> 6) * 2 + 1] = mp; }
    __syncthreads();
    if (t == 0) {
        float sumsq = red[0] + red[2], ssum = red[1] + red[3];
        float invB = 1.0f / (float)Brows;
        float mean = ssum * invB;
        float var  = sumsq * invB - mean * mean;
        float rstd = rsqrtf(var + 1e-3f);
        float sc   = rstd * gamma[n];
        ws[WS_SCALE + n] = sc;
        ws[WS_SHIFT + n] = beta[n] - mean * sc;
    }
}

// K0: pack W' = W * scale  -> fragment-major bf16 hi/lo (RNE). Runs AFTER k2.
__global__ void k0_packW(const float* __restrict__ W, const float* __restrict__ ws,
                         unsigned short* __restrict__ Whi, unsigned short* __restrict__ Wlo)
{
    int idx = blockIdx.x * 256 + threadIdx.x;   // 0..65535
    int k = idx >> 9, n = idx & 511;
    float v = W[idx] * ws[WS_SCALE + n];
    int c = k >> 5, j = k & 7, lane = ((k >> 3) & 3) * 16 + (n & 15), t = n >> 4;
    int dst = (((c * 32 + t) * 64 + lane) << 3) + j;
    unsigned short hi = f2bf(v);
    unsigned short lo = f2bf(v - bf2f(hi));
    Whi[dst] = hi;
    Wlo[dst] = lo;
}

// K3: swapped-operand fused kernel. LDS-staged W (global_load_lds, dbuf),
// then CANDIDATE-COMPACTED sparsemax: support subset {z > max-1} goes to an
// LDS list (reusing the dead staging buffer); lane r solves row r's Newton
// serially over ~L<<512 entries; entropy over support only (exact).
__global__ __launch_bounds__(512, 2) void k3_fused(
    const float* __restrict__ A, const unsigned short* __restrict__ Whi,
    const unsigned short* __restrict__ Wlo, const float* __restrict__ prior,
    float* __restrict__ out, float* __restrict__ ws)
{
    __shared__ char smem_raw[65536];   // GEMM: staging dbuf; tail: candidate lists
    __shared__ int s_cnt[128];
    short8 (*wb)[2][16][64] = (short8 (*)[2][16][64])smem_raw;
    float* cand = (float*)smem_raw;

    const int tid = threadIdx.x;
    const int wave = tid >> 6, lane = tid & 63, lg = lane >> 4, lm = lane & 15;
    const int r0 = blockIdx.x * 128 + wave * 16;

    // A fragments (B-operand of the swapped mfma): row = r0+lm, k = lg*8+j
    short8 ahi[4], alo[4];
    const float* arow = A + (size_t)(r0 + lm) * DIN + lg * 8;
#pragma unroll
    for (int c = 0; c < 4; ++c) {
        float4 f0 = *(const float4*)(arow + c * 32);
        float4 f1 = *(const float4*)(arow + c * 32 + 4);
        float fv[8] = {f0.x, f0.y, f0.z, f0.w, f1.x, f1.y, f1.z, f1.w};
#pragma unroll
        for (int j = 0; j < 8; ++j) {
            unsigned uv = __float_as_uint(fv[j]);
            float lo = fv[j] - __uint_as_float(uv & 0xFFFF0000u);
            ahi[c][j] = (short)(uv >> 16);
            alo[c][j] = (short)(__float_as_uint(lo) >> 16);
        }
    }

#define K3_STAGE(s, buf)                                                          \
    {                                                                             \
        const int H_ = (s) >> 2, c_ = (s) & 3;                                    \
        const unsigned short* srcH_ = Whi + (size_t)((c_ * 32 + H_ * 16) * 64) * 8;\
        const unsigned short* srcL_ = Wlo + (size_t)((c_ * 32 + H_ * 16) * 64) * 8;\
        _Pragma("unroll")                                                         \
        for (int i_ = 0; i_ < 4; ++i_) {                                          \
            int q_ = i_ * 512 + tid;                                              \
            const unsigned short* src_ = (q_ >> 10) ? srcL_ + (size_t)(q_ & 1023) * 8 \
                                                    : srcH_ + (size_t)(q_ & 1023) * 8; \
            __builtin_amdgcn_global_load_lds(                                     \
                (const __attribute__((address_space(1))) void*)src_,              \
                (__attribute__((address_space(3))) void*)&wb[buf][q_ >> 10][(q_ >> 6) & 15][q_ & 63], \
                16, 0, 0);                                                        \
        }                                                                         \
    }

    // acc[t][g] = X_bn[r=lm][n = t*16 + lg*4 + g]; init = shift[n]
    f32x4 acc[32];
#pragma unroll
    for (int t = 0; t < 32; ++t)
        acc[t] = *(const f32x4*)(ws + WS_SHIFT + t * 16 + lg * 4);

    K3_STAGE(0, 0);
    asm volatile("s_waitcnt vmcnt(0)" ::: "memory");
    __syncthreads();

#pragma unroll
    for (int H = 0; H < 2; ++H) {
#pragma unroll
        for (int c = 0; c < 4; ++c) {
            const int s = H * 4 + c;
            if (s == 0) { K3_STAGE(1, 1); }
            else if (s == 1) { K3_STAGE(2, 0); }
            else if (s == 2) { K3_STAGE(3, 1); }
            else if (s == 3) { K3_STAGE(4, 0); }
            else if (s == 4) { K3_STAGE(5, 1); }
            else if (s == 5) { K3_STAGE(6, 0); }
            else if (s == 6) { K3_STAGE(7, 1); }
            const int buf = s & 1;
#pragma unroll
            for (int t = 0; t < 16; ++t) {
                short8 h = wb[buf][0][t][lane];
                short8 l = wb[buf][1][t][lane];
                acc[H * 16 + t] = __builtin_amdgcn_mfma_f32_16x16x32_bf16(h, alo[c], acc[H * 16 + t], 0, 0, 0);
                acc[H * 16 + t] = __builtin_amdgcn_mfma_f32_16x16x32_bf16(l, ahi[c], acc[H * 16 + t], 0, 0, 0);
                acc[H * 16 + t] = __builtin_amdgcn_mfma_f32_16x16x32_bf16(h, ahi[c], acc[H * 16 + t], 0, 0, 0);
            }
            if (s < 7) {
                asm volatile("s_waitcnt vmcnt(0)" ::: "memory");
                __syncthreads();
            }
        }
        const float* prow = prior + (size_t)(r0 + lm) * UNITS + lg * 4;
#pragma unroll
        for (int t = 0; t < 16; ++t) {
            float4 p = *(const float4*)(prow + (H * 16 + t) * 16);
            acc[H * 16 + t][0] *= p.x;
            acc[H * 16 + t][1] *= p.y;
            acc[H * 16 + t][2] *= p.z;
            acc[H * 16 + t][3] *= p.w;
        }
    }

    // row max: in-lane over 128, then combine the row's 4 lanes (xor 16, 32)
    float m = acc[0][0];
#pragma unroll
    for (int t = 0; t < 32; ++t) {
#pragma unroll
        for (int g = 0; g < 4; ++g) m = fmaxf(m, acc[t][g]);
    }
    m = fmaxf(m, __shfl_xor(m, 16, 64));
    m = fmaxf(m, __shfl_xor(m, 32, 64));

    // ---- candidate compaction (LDS staging buffer is dead after the GEMM) ----
    __syncthreads();   // all waves done reading wb before cand overwrites it
    if (lane < 16) s_cnt[wave * 16 + lane] = 0;   // same-wave DS ordering suffices

    const int wrow = wave * 16 + lm;
    const float thr = m - 1.0f;
#pragma unroll
    for (int t = 0; t < 32; ++t) {
#pragma unroll
        for (int g = 0; g < 4; ++g) {
            float v = acc[t][g];
            if (v > thr) {
                int idx = atomicAdd(&s_cnt[wrow], 1);
                if (idx < CAP) cand[wrow * CAP + idx] = v;
            }
        }
    }

    // ---- per-row serial Newton (lane r = row r of this wave) ----
    float tau = thr;
    float ent = 0.f;
    int myc = (lane < 16) ? s_cnt[wave * 16 + lane] : 0;
    unsigned long long ovf = __ballot(myc > CAP);

    if (ovf == 0ull) {
        if (lane < 16) {
            const float* lst = cand + (wave * 16 + lane) * CAP;
            for (int it = 0; it < 24; ++it) {
                float S = 0.f, K = 0.f;
                for (int i2 = 0; i2 < myc; ++i2) {
                    float v = lst[i2];
                    if (v > tau) { S += v; K += 1.f; }
                }
                float nt = (S - 1.0f) / K;
                if (!(nt > tau)) break;
                tau = nt;
            }
            // entropy over the support only (zero-mask terms are exactly 0)
            for (int i2 = 0; i2 < myc; ++i2) {
                float v = lst[i2] - tau;
                if (v > 0.f) ent -= v * __logf(v + 1e-15f);
            }
        }
    } else {
        // fallback: full-scan ballot Newton (verified round-7 path)
        for (int it = 0; it < 24; ++it) {
            float S = 0.f, K = 0.f;
#pragma unroll
            for (int t = 0; t < 32; ++t) {
#pragma unroll
                for (int g = 0; g < 4; ++g) {
                    float v = acc[t][g];
                    if (v > tau) { S += v; K += 1.f; }
                }
            }
            S += __shfl_xor(S, 16, 64); S += __shfl_xor(S, 32, 64);
            K += __shfl_xor(K, 16, 64); K += __shfl_xor(K, 32, 64);
            float nt = (S - 1.0f) / K;
            int chg = (nt > tau);
            if (chg) tau = nt;
            if (__ballot(chg) == 0ull) break;
        }
#pragma unroll
        for (int t = 0; t < 32; ++t) {
#pragma unroll
            for (int g = 0; g < 4; ++g) {
                float v = fmaxf(acc[t][g] - tau, 0.f);
                ent -= v * __logf(v + 1e-15f);
            }
        }
    }

    // broadcast tau to the row's 4 lanes (no-op-correct in fallback too)
    tau = __shfl(tau, lm, 64);

    // ---- mask write (no per-element logs) ----
    float* orow = out + (size_t)(r0 + lm) * UNITS + lg * 4;
#pragma unroll
    for (int t = 0; t < 32; ++t) {
        float4 o;
        o.x = fmaxf(acc[t][0] - tau, 0.f);
        o.y = fmaxf(acc[t][1] - tau, 0.f);
        o.z = fmaxf(acc[t][2] - tau, 0.f);
        o.w = fmaxf(acc[t][3] - tau, 0.f);
        *(float4*)(orow + t * 16) = o;
    }

    // entropy reduce (serial path: lanes 0-15 hold row sums; fallback: all lanes)
#pragma unroll
    for (int off = 32; off; off >>= 1) ent += __shfl_xor(ent, off, 64);
    if (lane == 0)
        atomicAdd(&ws[WS_ESLOT + ((blockIdx.x * 8 + wave) & (N_ESLOT - 1))], ent);
#undef K3_STAGE
}

// K4: reduce entropy slots -> scalar loss
__global__ void k4_loss(const float* __restrict__ ws, float* __restrict__ out_loss,
                        int Brows)
{
    __shared__ float sh[512];
    int t = threadIdx.x;
    sh[t] = ws[WS_ESLOT + t];
    __syncthreads();
    for (int s = 256; s > 0; s >>= 1) {
        if (t < s) sh[t] += sh[t + s];
        __syncthreads();
    }
    if (t == 0) out_loss[0] = 1e-3f * (sh[0] / (float)Brows) * (1.0f / 3.0f);
}

extern "C" void kernel_launch(void* const* d_in, const int* in_sizes, int n_in,
                              void* d_out, int out_size, void* d_ws, size_t ws_size,
                              hipStream_t stream)
{
    const float* inputs = (const float*)d_in[0];
    const float* prior  = (const float*)d_in[1];
    const float* Wm     = (const float*)d_in[2];
    const float* gamma  = (const float*)d_in[3];
    const float* beta   = (const float*)d_in[4];
    float* out = (float*)d_out;
    float* ws  = (float*)d_ws;
    unsigned short* Whi = (unsigned short*)(ws + WS_WHI);
    unsigned short* Wlo = (unsigned short*)(ws + WS_WLO);
    const int Brows = in_sizes[1] / UNITS;   // 131072

    // d_out doubles as Gram-partial scratch (33.5 MB) before k3 overwrites it.
    float* Gpart = out;

    hipMemsetAsync(ws, 0, WS_ZERO_FLOATS * sizeof(float), stream);

    k1a_gram<<<GRAM_BLOCKS, 256, 0, stream>>>(inputs, Gpart, ws, Brows);
    k1b_sumG<<<64, 256, 0, stream>>>(Gpart, ws);
    k2_finalize<<<UNITS, 128, 0, stream>>>(Wm, gamma, beta, ws, Brows);
    k0_packW<<<256, 256, 0, stream>>>(Wm, ws, Whi, Wlo);   // W' = W*scale
    k3_fused<<<Brows / 128, 512, 0, stream>>>(inputs, Whi, Wlo, prior, out, ws);
    k4_loss<<<1, N_ESLOT, 0, stream>>>(ws, out + (size_t)Brows * UNITS, Brows);
}

// Round 10
// 281.603 us; speedup vs baseline: 1.1098x; 1.1098x over previous
//
#include <hip/hip_runtime.h>
#include <math.h>

typedef __attribute__((ext_vector_type(8))) short short8;
typedef __attribute__((ext_vector_type(4))) float f32x4;

#define UNITS 512
#define DIN 128

// ws float offsets:
#define WS_COLSA  0        // 8 slots x 128, colsum(A), atomic (zeroed)
#define WS_SCALE  1024     // 512
#define WS_SHIFT  1536     // 512
#define WS_ESLOT  2048     // 512 entropy slots, atomic (zeroed)
#define WS_GF     2560     // 16384, G final (128x128)
#define WS_WHI    19456    // 65536 ushorts (32768 floats)
#define WS_WLO    52224    // 65536 ushorts
#define N_ESLOT   512
#define WS_ZERO_FLOATS 2560

#define GRAM_BLOCKS 512    // G partials: GRAM_BLOCKS x 16384 floats in d_out scratch

__device__ __forceinline__ unsigned short f2bf(float f) {
    unsigned u = __float_as_uint(f);
    unsigned r = (u + 0x7FFFu + ((u >> 16) & 1u)) >> 16;   // RNE
    return (unsigned short)r;
}
__device__ __forceinline__ float bf2f(unsigned short h) {
    return __uint_as_float(((unsigned)h) << 16);
}

// K1a: Gram partials G_b = A_b^T A_b (3-term split-bf16 MFMA) + colsum(A).
__global__ __launch_bounds__(256) void k1a_gram(const float* __restrict__ A,
                                                float* __restrict__ Gpart,
                                                float* __restrict__ ws, int Brows)
{
    __shared__ float As[32][133];
    __shared__ float s_lds[128];
    const int t = threadIdx.x;
    const int wave = t >> 6, lane = t & 63, lg = lane >> 4, lm = lane & 15;
    const int rowsPerBlk = Brows / GRAM_BLOCKS;   // 256
    const int r0 = blockIdx.x * rowsPerBlk;

    if (t < 128) s_lds[t] = 0.f;
    float s_part[4] = {0.f, 0.f, 0.f, 0.f};

    f32x4 acc[16];
#pragma unroll
    for (int i = 0; i < 16; ++i) acc[i] = (f32x4){0.f, 0.f, 0.f, 0.f};

    for (int kk = 0; kk < rowsPerBlk; kk += 32) {
        __syncthreads();
#pragma unroll
        for (int i = 0; i < 4; ++i) {
            int fi = t + i * 256;
            int row = fi >> 5, c4 = (fi & 31) * 4;
            float4 v = *(const float4*)(A + (size_t)(r0 + kk + row) * DIN + c4);
            *(float4*)&As[row][c4] = v;
            s_part[0] += v.x; s_part[1] += v.y; s_part[2] += v.z; s_part[3] += v.w;
        }
        __syncthreads();

        short8 fh[8], fl[8];
#pragma unroll
        for (int f = 0; f < 8; ++f) {
#pragma unroll
            for (int j = 0; j < 8; ++j) {
                float v = As[lg * 8 + j][f * 16 + lm];
                unsigned uv = __float_as_uint(v);
                float lo = v - __uint_as_float(uv & 0xFFFF0000u);
                fh[f][j] = (short)(uv >> 16);
                fl[f][j] = (short)(__float_as_uint(lo) >> 16);
            }
        }
        short8 ah0, al0, ah1, al1;
#pragma unroll
        for (int j = 0; j < 8; ++j) {
            float v0 = As[lg * 8 + j][wave * 32 + lm];
            float v1 = As[lg * 8 + j][wave * 32 + 16 + lm];
            unsigned u0 = __float_as_uint(v0), u1 = __float_as_uint(v1);
            float l0 = v0 - __uint_as_float(u0 & 0xFFFF0000u);
            float l1 = v1 - __uint_as_float(u1 & 0xFFFF0000u);
            ah0[j] = (short)(u0 >> 16);
            al0[j] = (short)(__float_as_uint(l0) >> 16);
            ah1[j] = (short)(u1 >> 16);
            al1[j] = (short)(__float_as_uint(l1) >> 16);
        }

#pragma unroll
        for (int tj = 0; tj < 8; ++tj) {
            acc[tj]     = __builtin_amdgcn_mfma_f32_16x16x32_bf16(al0, fh[tj], acc[tj], 0, 0, 0);
            acc[tj]     = __builtin_amdgcn_mfma_f32_16x16x32_bf16(ah0, fl[tj], acc[tj], 0, 0, 0);
            acc[tj]     = __builtin_amdgcn_mfma_f32_16x16x32_bf16(ah0, fh[tj], acc[tj], 0, 0, 0);
            acc[8 + tj] = __builtin_amdgcn_mfma_f32_16x16x32_bf16(al1, fh[tj], acc[8 + tj], 0, 0, 0);
            acc[8 + tj] = __builtin_amdgcn_mfma_f32_16x16x32_bf16(ah1, fl[tj], acc[8 + tj], 0, 0, 0);
            acc[8 + tj] = __builtin_amdgcn_mfma_f32_16x16x32_bf16(ah1, fh[tj], acc[8 + tj], 0, 0, 0);
        }
    }

#pragma unroll
    for (int j = 0; j < 4; ++j) atomicAdd(&s_lds[(t & 31) * 4 + j], s_part[j]);
    __syncthreads();
    if (t < 128) atomicAdd(ws + WS_COLSA + (blockIdx.x & 7) * 128 + t, s_lds[t]);

    float* Gs = Gpart + (size_t)blockIdx.x * 16384;
#pragma unroll
    for (int a2 = 0; a2 < 2; ++a2) {
#pragma unroll
        for (int tj = 0; tj < 8; ++tj) {
#pragma unroll
            for (int g = 0; g < 4; ++g) {
                int gi = (2 * wave + a2) * 16 + lg * 4 + g;
                int gj = tj * 16 + lm;
                Gs[gi * 128 + gj] = acc[a2 * 8 + tj][g];
            }
        }
    }
}

// K1b: reduce GRAM_BLOCKS partials -> G final in ws
__global__ __launch_bounds__(256) void k1b_sumG(const float* __restrict__ Gpart,
                                                float* __restrict__ ws)
{
    int i = blockIdx.x * 256 + threadIdx.x;   // 0..16383
    float v = 0.f;
#pragma unroll 8
    for (int s = 0; s < GRAM_BLOCKS; ++s) v += Gpart[(size_t)s * 16384 + i];
    ws[WS_GF + i] = v;
}

// K2: per-column BN stats from Gram: mean = (colsum(A).w)/N, sumsq = w^T G w.
__global__ __launch_bounds__(128) void k2_finalize(
    const float* __restrict__ W, const float* __restrict__ gamma,
    const float* __restrict__ beta, float* __restrict__ ws, int Brows)
{
    __shared__ float wcol[128];
    __shared__ float red[4];
    const int t = threadIdx.x, n = blockIdx.x;
    wcol[t] = W[(size_t)t * UNITS + n];
    __syncthreads();
    const float* GF = ws + WS_GF;
    float q = 0.f;
#pragma unroll 8
    for (int i = 0; i < 128; ++i) q += GF[i * 128 + t] * wcol[i];
    q *= wcol[t];
    float csa = 0.f;
#pragma unroll
    for (int sl = 0; sl < 8; ++sl) csa += ws[WS_COLSA + sl * 128 + t];
    float mp = csa * wcol[t];
#pragma unroll
    for (int off = 32; off; off >>= 1) {
        q  += __shfl_xor(q, off, 64);
        mp += __shfl_xor(mp, off, 64);
    }
    if ((t & 63) == 0) { red[(t >> 6) * 2] = q; red[(t >> 6) * 2 + 1] = mp; }
    __syncthreads();
    if (t == 0) {
        float sumsq = red[0] + red[2], ssum = red[1] + red[3];
        float invB = 1.0f / (float)Brows;
        float mean = ssum * invB;
        float var  = sumsq * invB - mean * mean;
        float rstd = rsqrtf(var + 1e-3f);
        float sc   = rstd * gamma[n];
        ws[WS_SCALE + n] = sc;
        ws[WS_SHIFT + n] = beta[n] - mean * sc;
    }
}

// K0: pack W' = W * scale  -> fragment-major bf16 hi/lo (RNE). Runs AFTER k2.
__global__ void k0_packW(const float* __restrict__ W, const float* __restrict__ ws,
                         unsigned short* __restrict__ Whi, unsigned short* __restrict__ Wlo)
{
    int idx = blockIdx.x * 256 + threadIdx.x;   // 0..65535
    int k = idx >> 9, n = idx & 511;
    float v = W[idx] * ws[WS_SCALE + n];
    int c = k >> 5, j = k & 7, lane = ((k >> 3) & 3) * 16 + (n & 15), t = n >> 4;
    int dst = (((c * 32 + t) * 64 + lane) << 3) + j;
    unsigned short hi = f2bf(v);
    unsigned short lo = f2bf(v - bf2f(hi));
    Whi[dst] = hi;
    Wlo[dst] = lo;
}

// SWZ: XOR-swizzle of a 16B-chunk index within a 32-chunk (512B) row segment.
// Involution; maps 64B lines to 64B lines (bits>=2 only) -> global coalescing
// preserved; spreads LDS banks across rows for the transposed read/write.
#define SWZ(row, s) ((s) ^ (((row) & 7) << 2))

// K3: swapped-operand fused kernel. GEMM: LDS-staged W (global_load_lds, dbuf,
// 8 stages). Tail: prior applied via 4x 64KB LDS TRANSPOSES (coalesced global
// side), in-register Newton sparsemax (zero barriers), entropy, and out written
// via 4x inverse LDS transposes (coalesced stores).
__global__ __launch_bounds__(512, 2) void k3_fused(
    const float* __restrict__ A, const unsigned short* __restrict__ Whi,
    const unsigned short* __restrict__ Wlo, const float* __restrict__ prior,
    float* __restrict__ out, float* __restrict__ ws)
{
    __shared__ float4 smem4[4096];   // 64 KB: GEMM W-staging dbuf, then transpose buf
    short8 (*wb)[2][16][64] = (short8 (*)[2][16][64])smem4;

    const int tid = threadIdx.x;
    const int wave = tid >> 6, lane = tid & 63, lg = lane >> 4, lm = lane & 15;
    const int r0 = blockIdx.x * 128 + wave * 16;
    const int r0blk = blockIdx.x * 128;

    // A fragments (B-operand of the swapped mfma): row = r0+lm, k = lg*8+j
    short8 ahi[4], alo[4];
    const float* arow = A + (size_t)(r0 + lm) * DIN + lg * 8;
#pragma unroll
    for (int c = 0; c < 4; ++c) {
        float4 f0 = *(const float4*)(arow + c * 32);
        float4 f1 = *(const float4*)(arow + c * 32 + 4);
        float fv[8] = {f0.x, f0.y, f0.z, f0.w, f1.x, f1.y, f1.z, f1.w};
#pragma unroll
        for (int j = 0; j < 8; ++j) {
            unsigned uv = __float_as_uint(fv[j]);
            float lo = fv[j] - __uint_as_float(uv & 0xFFFF0000u);
            ahi[c][j] = (short)(uv >> 16);
            alo[c][j] = (short)(__float_as_uint(lo) >> 16);
        }
    }

#define K3_STAGE(s, buf)                                                          \
    {                                                                             \
        const int H_ = (s) >> 2, c_ = (s) & 3;                                    \
        const unsigned short* srcH_ = Whi + (size_t)((c_ * 32 + H_ * 16) * 64) * 8;\
        const unsigned short* srcL_ = Wlo + (size_t)((c_ * 32 + H_ * 16) * 64) * 8;\
        _Pragma("unroll")                                                         \
        for (int i_ = 0; i_ < 4; ++i_) {                                          \
            int q_ = i_ * 512 + tid;                                              \
            const unsigned short* src_ = (q_ >> 10) ? srcL_ + (size_t)(q_ & 1023) * 8 \
                                                    : srcH_ + (size_t)(q_ & 1023) * 8; \
            __builtin_amdgcn_global_load_lds(                                     \
                (const __attribute__((address_space(1))) void*)src_,              \
                (__attribute__((address_space(3))) void*)&wb[buf][q_ >> 10][(q_ >> 6) & 15][q_ & 63], \
                16, 0, 0);                                                        \
        }                                                                         \
    }

    // acc[t][g] = X_bn[r=lm][n = t*16 + lg*4 + g]; init = shift[n]
    f32x4 acc[32];
#pragma unroll
    for (int t = 0; t < 32; ++t)
        acc[t] = *(const f32x4*)(ws + WS_SHIFT + t * 16 + lg * 4);

    K3_STAGE(0, 0);
    asm volatile("s_waitcnt vmcnt(0)" ::: "memory");
    __syncthreads();

#pragma unroll
    for (int H = 0; H < 2; ++H) {
#pragma unroll
        for (int c = 0; c < 4; ++c) {
            const int s = H * 4 + c;
            if (s == 0) { K3_STAGE(1, 1); }
            else if (s == 1) { K3_STAGE(2, 0); }
            else if (s == 2) { K3_STAGE(3, 1); }
            else if (s == 3) { K3_STAGE(4, 0); }
            else if (s == 4) { K3_STAGE(5, 1); }
            else if (s == 5) { K3_STAGE(6, 0); }
            else if (s == 6) { K3_STAGE(7, 1); }
            const int buf = s & 1;
#pragma unroll
            for (int t = 0; t < 16; ++t) {
                short8 h = wb[buf][0][t][lane];
                short8 l = wb[buf][1][t][lane];
                acc[H * 16 + t] = __builtin_amdgcn_mfma_f32_16x16x32_bf16(h, alo[c], acc[H * 16 + t], 0, 0, 0);
                acc[H * 16 + t] = __builtin_amdgcn_mfma_f32_16x16x32_bf16(l, ahi[c], acc[H * 16 + t], 0, 0, 0);
                acc[H * 16 + t] = __builtin_amdgcn_mfma_f32_16x16x32_bf16(h, ahi[c], acc[H * 16 + t], 0, 0, 0);
            }
            if (s < 7) {
                asm volatile("s_waitcnt vmcnt(0)" ::: "memory");
                __syncthreads();
            }
        }
    }

    // ---- prior via 4 quarter transposes: [128 rows][128 cols] = 64 KB each ----
    const int rr = wave * 16 + lm;        // this lane's block-local row
#pragma unroll
    for (int Q = 0; Q < 4; ++Q) {
        __syncthreads();   // buffer free (GEMM wb or previous quarter's reads)
        // stage lane-linear: LDS[row][s] = prior[r0blk+row][Q*128 + SWZ(row,s)*4 ..]
#pragma unroll
        for (int i = 0; i < 8; ++i) {
            int qq = i * 512 + tid;               // 0..4095
            int row = qq >> 5, s5 = qq & 31;
            const float* src = prior + (size_t)(r0blk + row) * UNITS + Q * 128 + SWZ(row, s5) * 4;
            __builtin_amdgcn_global_load_lds(
                (const __attribute__((address_space(1))) void*)src,
                (__attribute__((address_space(3))) void*)&smem4[qq], 16, 0, 0);
        }
        asm volatile("s_waitcnt vmcnt(0)" ::: "memory");
        __syncthreads();
#pragma unroll
        for (int tl = 0; tl < 8; ++tl) {
            float4 p = smem4[rr * 32 + SWZ(rr, tl * 4 + lg)];
            acc[Q * 8 + tl][0] *= p.x;
            acc[Q * 8 + tl][1] *= p.y;
            acc[Q * 8 + tl][2] *= p.z;
            acc[Q * 8 + tl][3] *= p.w;
        }
    }

    // ---- row max: in-lane over 128, then the row's 4 lanes (xor 16, 32) ----
    float m = acc[0][0];
#pragma unroll
    for (int t = 0; t < 32; ++t) {
#pragma unroll
        for (int g = 0; g < 4; ++g) m = fmaxf(m, acc[t][g]);
    }
    m = fmaxf(m, __shfl_xor(m, 16, 64));
    m = fmaxf(m, __shfl_xor(m, 32, 64));

    // ---- Newton on f(tau)=sum(relu(z-tau))-1 (exact, monotone, in-reg) ----
    float tau = m - 1.0f;
    for (int it = 0; it < 24; ++it) {
        float S = 0.f, K = 0.f;
#pragma unroll
        for (int t = 0; t < 32; ++t) {
#pragma unroll
            for (int g = 0; g < 4; ++g) {
                float v = acc[t][g];
                if (v > tau) { S += v; K += 1.f; }
            }
        }
        S += __shfl_xor(S, 16, 64); S += __shfl_xor(S, 32, 64);
        K += __shfl_xor(K, 16, 64); K += __shfl_xor(K, 32, 64);
        float nt = (S - 1.0f) / K;
        int chg = (nt > tau);
        if (chg) tau = nt;
        if (__ballot(chg) == 0ull) break;
    }

    // ---- mask + entropy, written via 4 inverse quarter transposes ----
    float ent = 0.f;
#pragma unroll
    for (int Q = 0; Q < 4; ++Q) {
        __syncthreads();   // buffer free from previous quarter's stores
#pragma unroll
        for (int tl = 0; tl < 8; ++tl) {
            float4 o;
            float v0 = fmaxf(acc[Q * 8 + tl][0] - tau, 0.f);
            float v1 = fmaxf(acc[Q * 8 + tl][1] - tau, 0.f);
            float v2 = fmaxf(acc[Q * 8 + tl][2] - tau, 0.f);
            float v3 = fmaxf(acc[Q * 8 + tl][3] - tau, 0.f);
            o.x = v0; o.y = v1; o.z = v2; o.w = v3;
            ent -= v0 * __logf(v0 + 1e-15f);
            ent -= v1 * __logf(v1 + 1e-15f);
            ent -= v2 * __logf(v2 + 1e-15f);
            ent -= v3 * __logf(v3 + 1e-15f);
            smem4[rr * 32 + SWZ(rr, tl * 4 + lg)] = o;
        }
        __syncthreads();
        // coalesced stores: out[r0blk+row][Q*128 + SWZ(row,s)*4..] = LDS[row][s]
#pragma unroll
        for (int i = 0; i < 8; ++i) {
            int qq = i * 512 + tid;
            int row = qq >> 5, s5 = qq & 31;
            *(float4*)(out + (size_t)(r0blk + row) * UNITS + Q * 128 + SWZ(row, s5) * 4) = smem4[qq];
        }
    }

#pragma unroll
    for (int off = 32; off; off >>= 1) ent += __shfl_xor(ent, off, 64);
    if (lane == 0)
        atomicAdd(&ws[WS_ESLOT + ((blockIdx.x * 8 + wave) & (N_ESLOT - 1))], ent);
#undef K3_STAGE
}

// K4: reduce entropy slots -> scalar loss
__global__ void k4_loss(const float* __restrict__ ws, float* __restrict__ out_loss,
                        int Brows)
{
    __shared__ float sh[512];
    int t = threadIdx.x;
    sh[t] = ws[WS_ESLOT + t];
    __syncthreads();
    for (int s = 256; s > 0; s >>= 1) {
        if (t < s) sh[t] += sh[t + s];
        __syncthreads();
    }
    if (t == 0) out_loss[0] = 1e-3f * (sh[0] / (float)Brows) * (1.0f / 3.0f);
}

extern "C" void kernel_launch(void* const* d_in, const int* in_sizes, int n_in,
                              void* d_out, int out_size, void* d_ws, size_t ws_size,
                              hipStream_t stream)
{
    const float* inputs = (const float*)d_in[0];
    const float* prior  = (const float*)d_in[1];
    const float* Wm     = (const float*)d_in[2];
    const float* gamma  = (const float*)d_in[3];
    const float* beta   = (const float*)d_in[4];
    float* out = (float*)d_out;
    float* ws  = (float*)d_ws;
    unsigned short* Whi = (unsigned short*)(ws + WS_WHI);
    unsigned short* Wlo = (unsigned short*)(ws + WS_WLO);
    const int Brows = in_sizes[1] / UNITS;   // 131072

    // d_out doubles as Gram-partial scratch (33.5 MB) before k3 overwrites it.
    float* Gpart = out;

    hipMemsetAsync(ws, 0, WS_ZERO_FLOATS * sizeof(float), stream);

    k1a_gram<<<GRAM_BLOCKS, 256, 0, stream>>>(inputs, Gpart, ws, Brows);
    k1b_sumG<<<64, 256, 0, stream>>>(Gpart, ws);
    k2_finalize<<<UNITS, 128, 0, stream>>>(Wm, gamma, beta, ws, Brows);
    k0_packW<<<256, 256, 0, stream>>>(Wm, ws, Whi, Wlo);   // W' = W*scale
    k3_fused<<<Brows / 128, 512, 0, stream>>>(inputs, Whi, Wlo, prior, out, ws);
    k4_loss<<<1, N_ESLOT, 0, stream>>>(ws, out + (size_t)Brows * UNITS, Brows);
}

// Round 11
// 260.628 us; speedup vs baseline: 1.1991x; 1.0805x over previous
//
#include <hip/hip_runtime.h>
#include <math.h>

typedef __attribute__((ext_vector_type(8))) short short8;
typedef __attribute__((ext_vector_type(4))) float f32x4;

#define UNITS 512
#define DIN 128

// ws float offsets:
#define WS_COLSA  0        // 8 slots x 128, colsum(A), atomic (zeroed)
#define WS_SCALE  1024     // 512
#define WS_SHIFT  1536     // 512
#define WS_ESLOT  2048     // 512 entropy slots, atomic (zeroed)
#define WS_GF     2560     // 16384, G final (128x128)
#define WS_WHI    19456    // 65536 ushorts (32768 floats)
#define WS_WLO    52224    // 65536 ushorts
#define N_ESLOT   512
#define WS_ZERO_FLOATS 2560

#define GRAM_BLOCKS 512    // G partials: GRAM_BLOCKS x 16384 floats in d_out scratch

__device__ __forceinline__ unsigned short f2bf(float f) {
    unsigned u = __float_as_uint(f);
    unsigned r = (u + 0x7FFFu + ((u >> 16) & 1u)) >> 16;   // RNE
    return (unsigned short)r;
}
__device__ __forceinline__ float bf2f(unsigned short h) {
    return __uint_as_float(((unsigned)h) << 16);
}

// K1a: Gram partials G_b = A_b^T A_b (3-term split-bf16 MFMA) + colsum(A).
__global__ __launch_bounds__(256) void k1a_gram(const float* __restrict__ A,
                                                float* __restrict__ Gpart,
                                                float* __restrict__ ws, int Brows)
{
    __shared__ float As[32][133];
    __shared__ float s_lds[128];
    const int t = threadIdx.x;
    const int wave = t >> 6, lane = t & 63, lg = lane >> 4, lm = lane & 15;
    const int rowsPerBlk = Brows / GRAM_BLOCKS;   // 256
    const int r0 = blockIdx.x * rowsPerBlk;

    if (t < 128) s_lds[t] = 0.f;
    float s_part[4] = {0.f, 0.f, 0.f, 0.f};

    f32x4 acc[16];
#pragma unroll
    for (int i = 0; i < 16; ++i) acc[i] = (f32x4){0.f, 0.f, 0.f, 0.f};

    for (int kk = 0; kk < rowsPerBlk; kk += 32) {
        __syncthreads();
#pragma unroll
        for (int i = 0; i < 4; ++i) {
            int fi = t + i * 256;
            int row = fi >> 5, c4 = (fi & 31) * 4;
            float4 v = *(const float4*)(A + (size_t)(r0 + kk + row) * DIN + c4);
            *(float4*)&As[row][c4] = v;
            s_part[0] += v.x; s_part[1] += v.y; s_part[2] += v.z; s_part[3] += v.w;
        }
        __syncthreads();

        short8 fh[8], fl[8];
#pragma unroll
        for (int f = 0; f < 8; ++f) {
#pragma unroll
            for (int j = 0; j < 8; ++j) {
                float v = As[lg * 8 + j][f * 16 + lm];
                unsigned uv = __float_as_uint(v);
                float lo = v - __uint_as_float(uv & 0xFFFF0000u);
                fh[f][j] = (short)(uv >> 16);
                fl[f][j] = (short)(__float_as_uint(lo) >> 16);
            }
        }
        short8 ah0, al0, ah1, al1;
#pragma unroll
        for (int j = 0; j < 8; ++j) {
            float v0 = As[lg * 8 + j][wave * 32 + lm];
            float v1 = As[lg * 8 + j][wave * 32 + 16 + lm];
            unsigned u0 = __float_as_uint(v0), u1 = __float_as_uint(v1);
            float l0 = v0 - __uint_as_float(u0 & 0xFFFF0000u);
            float l1 = v1 - __uint_as_float(u1 & 0xFFFF0000u);
            ah0[j] = (short)(u0 >> 16);
            al0[j] = (short)(__float_as_uint(l0) >> 16);
            ah1[j] = (short)(u1 >> 16);
            al1[j] = (short)(__float_as_uint(l1) >> 16);
        }

#pragma unroll
        for (int tj = 0; tj < 8; ++tj) {
            acc[tj]     = __builtin_amdgcn_mfma_f32_16x16x32_bf16(al0, fh[tj], acc[tj], 0, 0, 0);
            acc[tj]     = __builtin_amdgcn_mfma_f32_16x16x32_bf16(ah0, fl[tj], acc[tj], 0, 0, 0);
            acc[tj]     = __builtin_amdgcn_mfma_f32_16x16x32_bf16(ah0, fh[tj], acc[tj], 0, 0, 0);
            acc[8 + tj] = __builtin_amdgcn_mfma_f32_16x16x32_bf16(al1, fh[tj], acc[8 + tj], 0, 0, 0);
            acc[8 + tj] = __builtin_amdgcn_mfma_f32_16x16x32_bf16(ah1, fl[tj], acc[8 + tj], 0, 0, 0);
            acc[8 + tj] = __builtin_amdgcn_mfma_f32_16x16x32_bf16(ah1, fh[tj], acc[8 + tj], 0, 0, 0);
        }
    }

#pragma unroll
    for (int j = 0; j < 4; ++j) atomicAdd(&s_lds[(t & 31) * 4 + j], s_part[j]);
    __syncthreads();
    if (t < 128) atomicAdd(ws + WS_COLSA + (blockIdx.x & 7) * 128 + t, s_lds[t]);

    float* Gs = Gpart + (size_t)blockIdx.x * 16384;
#pragma unroll
    for (int a2 = 0; a2 < 2; ++a2) {
#pragma unroll
        for (int tj = 0; tj < 8; ++tj) {
#pragma unroll
            for (int g = 0; g < 4; ++g) {
                int gi = (2 * wave + a2) * 16 + lg * 4 + g;
                int gj = tj * 16 + lm;
                Gs[gi * 128 + gj] = acc[a2 * 8 + tj][g];
            }
        }
    }
}

// K1b: reduce GRAM_BLOCKS partials -> G final in ws
__global__ __launch_bounds__(256) void k1b_sumG(const float* __restrict__ Gpart,
                                                float* __restrict__ ws)
{
    int i = blockIdx.x * 256 + threadIdx.x;   // 0..16383
    float v = 0.f;
#pragma unroll 8
    for (int s = 0; s < GRAM_BLOCKS; ++s) v += Gpart[(size_t)s * 16384 + i];
    ws[WS_GF + i] = v;
}

// K2: per-column BN stats from Gram (mean = colsum(A).w/N, sumsq = w^T G w)
// FUSED with the W'-pack: block n also packs col n of W' = W*scale into the
// fragment-major bf16 hi/lo arrays (k0 eliminated).
__global__ __launch_bounds__(128) void k2_finalize(
    const float* __restrict__ W, const float* __restrict__ gamma,
    const float* __restrict__ beta, float* __restrict__ ws,
    unsigned short* __restrict__ Whi, unsigned short* __restrict__ Wlo, int Brows)
{
    __shared__ float wcol[128];
    __shared__ float red[4];
    __shared__ float sres;
    const int t = threadIdx.x, n = blockIdx.x;
    wcol[t] = W[(size_t)t * UNITS + n];
    __syncthreads();
    const float* GF = ws + WS_GF;
    float q = 0.f;
#pragma unroll 8
    for (int i = 0; i < 128; ++i) q += GF[i * 128 + t] * wcol[i];
    q *= wcol[t];
    float csa = 0.f;
#pragma unroll
    for (int sl = 0; sl < 8; ++sl) csa += ws[WS_COLSA + sl * 128 + t];
    float mp = csa * wcol[t];
#pragma unroll
    for (int off = 32; off; off >>= 1) {
        q  += __shfl_xor(q, off, 64);
        mp += __shfl_xor(mp, off, 64);
    }
    if ((t & 63) == 0) { red[(t >> 6) * 2] = q; red[(t >> 6) * 2 + 1] = mp; }
    __syncthreads();
    if (t == 0) {
        float sumsq = red[0] + red[2], ssum = red[1] + red[3];
        float invB = 1.0f / (float)Brows;
        float mean = ssum * invB;
        float var  = sumsq * invB - mean * mean;
        float rstd = rsqrtf(var + 1e-3f);
        float sc   = rstd * gamma[n];
        ws[WS_SCALE + n] = sc;
        ws[WS_SHIFT + n] = beta[n] - mean * sc;
        sres = sc;
    }
    __syncthreads();
    // pack element (k = t, col = n) of W' = W*scale
    float v = wcol[t] * sres;
    int c = t >> 5, j = t & 7, lane = ((t >> 3) & 3) * 16 + (n & 15), t8 = n >> 4;
    int dst = (((c * 32 + t8) * 64 + lane) << 3) + j;
    unsigned short hi = f2bf(v);
    Whi[dst] = hi;
    Wlo[dst] = f2bf(v - bf2f(hi));
}

// K3: swapped-operand fused kernel. 256 thr = 4 waves x 16 rows = 64 rows;
// W LDS-staged (global_load_lds, dbuf, 8 stages). Two blocks co-resident per
// CU -> GEMM phase of one block overlaps the VALU/HBM tail of the other.
// Tail: direct-global prior/store (r8-verified), in-register Newton, entropy.
__global__ __launch_bounds__(256, 2) void k3_fused(
    const float* __restrict__ A, const unsigned short* __restrict__ Whi,
    const unsigned short* __restrict__ Wlo, const float* __restrict__ prior,
    float* __restrict__ out, float* __restrict__ ws)
{
    __shared__ short8 wb[2][2][16][64];   // [dbuf][hi/lo][tile][lane] = 64 KB

    const int tid = threadIdx.x;
    const int wave = tid >> 6, lane = tid & 63, lg = lane >> 4, lm = lane & 15;
    const int r0 = blockIdx.x * 64 + wave * 16;

    // A fragments (B-operand of the swapped mfma): row = r0+lm, k = lg*8+j
    short8 ahi[4], alo[4];
    const float* arow = A + (size_t)(r0 + lm) * DIN + lg * 8;
#pragma unroll
    for (int c = 0; c < 4; ++c) {
        float4 f0 = *(const float4*)(arow + c * 32);
        float4 f1 = *(const float4*)(arow + c * 32 + 4);
        float fv[8] = {f0.x, f0.y, f0.z, f0.w, f1.x, f1.y, f1.z, f1.w};
#pragma unroll
        for (int j = 0; j < 8; ++j) {
            unsigned uv = __float_as_uint(fv[j]);
            float lo = fv[j] - __uint_as_float(uv & 0xFFFF0000u);
            ahi[c][j] = (short)(uv >> 16);
            alo[c][j] = (short)(__float_as_uint(lo) >> 16);
        }
    }

    // stage s: 2048 x 16B chunks over 256 threads (8 per thread). q = i*256+tid;
    // which=q>>10, tile=(q>>6)&15, slot=q&63 (= lane within its wave -> LDS dst
    // is wave-uniform base + lane*16, satisfying global_load_lds).
#define K3_STAGE(s, buf)                                                          \
    {                                                                             \
        const int H_ = (s) >> 2, c_ = (s) & 3;                                    \
        const unsigned short* srcH_ = Whi + (size_t)((c_ * 32 + H_ * 16) * 64) * 8;\
        const unsigned short* srcL_ = Wlo + (size_t)((c_ * 32 + H_ * 16) * 64) * 8;\
        _Pragma("unroll")                                                         \
        for (int i_ = 0; i_ < 8; ++i_) {                                          \
            int q_ = i_ * 256 + tid;                                              \
            const unsigned short* src_ = (q_ >> 10) ? srcL_ + (size_t)(q_ & 1023) * 8 \
                                                    : srcH_ + (size_t)(q_ & 1023) * 8; \
            __builtin_amdgcn_global_load_lds(                                     \
                (const __attribute__((address_space(1))) void*)src_,              \
                (__attribute__((address_space(3))) void*)&wb[buf][q_ >> 10][(q_ >> 6) & 15][q_ & 63], \
                16, 0, 0);                                                        \
        }                                                                         \
    }

    // acc[t][g] = X_bn[r=lm][n = t*16 + lg*4 + g]; init = shift[n]
    f32x4 acc[32];
#pragma unroll
    for (int t = 0; t < 32; ++t)
        acc[t] = *(const f32x4*)(ws + WS_SHIFT + t * 16 + lg * 4);

    K3_STAGE(0, 0);
    asm volatile("s_waitcnt vmcnt(0)" ::: "memory");
    __syncthreads();

    float m = -3.4e38f;   // row max, folded per col-half
#pragma unroll
    for (int H = 0; H < 2; ++H) {
#pragma unroll
        for (int c = 0; c < 4; ++c) {
            const int s = H * 4 + c;
            if (s == 0) { K3_STAGE(1, 1); }
            else if (s == 1) { K3_STAGE(2, 0); }
            else if (s == 2) { K3_STAGE(3, 1); }
            else if (s == 3) { K3_STAGE(4, 0); }
            else if (s == 4) { K3_STAGE(5, 1); }
            else if (s == 5) { K3_STAGE(6, 0); }
            else if (s == 6) { K3_STAGE(7, 1); }
            const int buf = s & 1;
#pragma unroll
            for (int t = 0; t < 16; ++t) {
                short8 h = wb[buf][0][t][lane];
                short8 l = wb[buf][1][t][lane];
                acc[H * 16 + t] = __builtin_amdgcn_mfma_f32_16x16x32_bf16(h, alo[c], acc[H * 16 + t], 0, 0, 0);
                acc[H * 16 + t] = __builtin_amdgcn_mfma_f32_16x16x32_bf16(l, ahi[c], acc[H * 16 + t], 0, 0, 0);
                acc[H * 16 + t] = __builtin_amdgcn_mfma_f32_16x16x32_bf16(h, ahi[c], acc[H * 16 + t], 0, 0, 0);
            }
            if (s < 7) {
                asm volatile("s_waitcnt vmcnt(0)" ::: "memory");
                __syncthreads();
            }
        }
        // prior-mul + max for this col-half (overlaps next half's prefetch)
        const float* prow = prior + (size_t)(r0 + lm) * UNITS + lg * 4;
#pragma unroll
        for (int t = 0; t < 16; ++t) {
            float4 p = *(const float4*)(prow + (H * 16 + t) * 16);
            acc[H * 16 + t][0] *= p.x;
            acc[H * 16 + t][1] *= p.y;
            acc[H * 16 + t][2] *= p.z;
            acc[H * 16 + t][3] *= p.w;
            m = fmaxf(m, fmaxf(fmaxf(acc[H * 16 + t][0], acc[H * 16 + t][1]),
                               fmaxf(acc[H * 16 + t][2], acc[H * 16 + t][3])));
        }
    }

    // combine the row's 4 lanes (xor 16, 32)
    m = fmaxf(m, __shfl_xor(m, 16, 64));
    m = fmaxf(m, __shfl_xor(m, 32, 64));

    // Newton on f(tau)=sum(relu(z-tau))-1: monotone tau, exact fixed point.
    float tau = m - 1.0f;
    for (int it = 0; it < 24; ++it) {
        float S = 0.f, K = 0.f;
#pragma unroll
        for (int t = 0; t < 32; ++t) {
#pragma unroll
            for (int g = 0; g < 4; ++g) {
                float v = acc[t][g];
                if (v > tau) { S += v; K += 1.f; }
            }
        }
        S += __shfl_xor(S, 16, 64); S += __shfl_xor(S, 32, 64);
        K += __shfl_xor(K, 16, 64); K += __shfl_xor(K, 32, 64);
        float nt = (S - 1.0f) / K;
        int chg = (nt > tau);
        if (chg) tau = nt;
        if (__ballot(chg) == 0ull) break;
    }

    // mask + entropy + float4 store
    float ent = 0.f;
    float* orow = out + (size_t)(r0 + lm) * UNITS + lg * 4;
#pragma unroll
    for (int t = 0; t < 32; ++t) {
        float4 o;
        float v0 = fmaxf(acc[t][0] - tau, 0.f);
        float v1 = fmaxf(acc[t][1] - tau, 0.f);
        float v2 = fmaxf(acc[t][2] - tau, 0.f);
        float v3 = fmaxf(acc[t][3] - tau, 0.f);
        o.x = v0; o.y = v1; o.z = v2; o.w = v3;
        ent -= v0 * __logf(v0 + 1e-15f);
        ent -= v1 * __logf(v1 + 1e-15f);
        ent -= v2 * __logf(v2 + 1e-15f);
        ent -= v3 * __logf(v3 + 1e-15f);
        *(float4*)(orow + t * 16) = o;
    }
#pragma unroll
    for (int off = 32; off; off >>= 1) ent += __shfl_xor(ent, off, 64);
    if (lane == 0)
        atomicAdd(&ws[WS_ESLOT + ((blockIdx.x * 4 + wave) & (N_ESLOT - 1))], ent);
#undef K3_STAGE
}

// K4: reduce entropy slots -> scalar loss
__global__ void k4_loss(const float* __restrict__ ws, float* __restrict__ out_loss,
                        int Brows)
{
    __shared__ float sh[512];
    int t = threadIdx.x;
    sh[t] = ws[WS_ESLOT + t];
    __syncthreads();
    for (int s = 256; s > 0; s >>= 1) {
        if (t < s) sh[t] += sh[t + s];
        __syncthreads();
    }
    if (t == 0) out_loss[0] = 1e-3f * (sh[0] / (float)Brows) * (1.0f / 3.0f);
}

extern "C" void kernel_launch(void* const* d_in, const int* in_sizes, int n_in,
                              void* d_out, int out_size, void* d_ws, size_t ws_size,
                              hipStream_t stream)
{
    const float* inputs = (const float*)d_in[0];
    const float* prior  = (const float*)d_in[1];
    const float* Wm     = (const float*)d_in[2];
    const float* gamma  = (const float*)d_in[3];
    const float* beta   = (const float*)d_in[4];
    float* out = (float*)d_out;
    float* ws  = (float*)d_ws;
    unsigned short* Whi = (unsigned short*)(ws + WS_WHI);
    unsigned short* Wlo = (unsigned short*)(ws + WS_WLO);
    const int Brows = in_sizes[1] / UNITS;   // 131072

    // d_out doubles as Gram-partial scratch (33.5 MB) before k3 overwrites it.
    float* Gpart = out;

    hipMemsetAsync(ws, 0, WS_ZERO_FLOATS * sizeof(float), stream);

    k1a_gram<<<GRAM_BLOCKS, 256, 0, stream>>>(inputs, Gpart, ws, Brows);
    k1b_sumG<<<64, 256, 0, stream>>>(Gpart, ws);
    k2_finalize<<<UNITS, 128, 0, stream>>>(Wm, gamma, beta, ws, Whi, Wlo, Brows);
    k3_fused<<<Brows / 64, 256, 0, stream>>>(inputs, Whi, Wlo, prior, out, ws);
    k4_loss<<<1, N_ESLOT, 0, stream>>>(ws, out + (size_t)Brows * UNITS, Brows);
}

// Round 12
// 260.456 us; speedup vs baseline: 1.1999x; 1.0007x over previous
//
#include <hip/hip_runtime.h>
#include <math.h>

typedef __attribute__((ext_vector_type(8))) short short8;
typedef __attribute__((ext_vector_type(4))) float f32x4;

#define UNITS 512
#define DIN 128

// ws float offsets:
#define WS_COLSA  0        // 8 slots x 128, colsum(A), atomic (zeroed)
#define WS_SCALE  1024     // 512
#define WS_SHIFT  1536     // 512
#define WS_ESLOT  2048     // 512 entropy slots, atomic (zeroed)
#define WS_GF     2560     // 16384, G final (128x128)
#define WS_WHI    19456    // 65536 ushorts (32768 floats)
#define WS_WLO    52224    // 65536 ushorts
#define N_ESLOT   512
#define WS_ZERO_FLOATS 2560

#define GRAM_BLOCKS 512    // G partials: GRAM_BLOCKS x 16384 floats in d_out scratch
#define NCAP 64            // per-lane candidate slots (64 KB / 4B / 256 threads)

__device__ __forceinline__ unsigned short f2bf(float f) {
    unsigned u = __float_as_uint(f);
    unsigned r = (u + 0x7FFFu + ((u >> 16) & 1u)) >> 16;   // RNE
    return (unsigned short)r;
}
__device__ __forceinline__ float bf2f(unsigned short h) {
    return __uint_as_float(((unsigned)h) << 16);
}

// K1a: Gram partials G_b = A_b^T A_b (3-term split-bf16 MFMA) + colsum(A).
__global__ __launch_bounds__(256) void k1a_gram(const float* __restrict__ A,
                                                float* __restrict__ Gpart,
                                                float* __restrict__ ws, int Brows)
{
    __shared__ float As[32][133];
    __shared__ float s_lds[128];
    const int t = threadIdx.x;
    const int wave = t >> 6, lane = t & 63, lg = lane >> 4, lm = lane & 15;
    const int rowsPerBlk = Brows / GRAM_BLOCKS;   // 256
    const int r0 = blockIdx.x * rowsPerBlk;

    if (t < 128) s_lds[t] = 0.f;
    float s_part[4] = {0.f, 0.f, 0.f, 0.f};

    f32x4 acc[16];
#pragma unroll
    for (int i = 0; i < 16; ++i) acc[i] = (f32x4){0.f, 0.f, 0.f, 0.f};

    for (int kk = 0; kk < rowsPerBlk; kk += 32) {
        __syncthreads();
#pragma unroll
        for (int i = 0; i < 4; ++i) {
            int fi = t + i * 256;
            int row = fi >> 5, c4 = (fi & 31) * 4;
            float4 v = *(const float4*)(A + (size_t)(r0 + kk + row) * DIN + c4);
            *(float4*)&As[row][c4] = v;
            s_part[0] += v.x; s_part[1] += v.y; s_part[2] += v.z; s_part[3] += v.w;
        }
        __syncthreads();

        short8 fh[8], fl[8];
#pragma unroll
        for (int f = 0; f < 8; ++f) {
#pragma unroll
            for (int j = 0; j < 8; ++j) {
                float v = As[lg * 8 + j][f * 16 + lm];
                unsigned uv = __float_as_uint(v);
                float lo = v - __uint_as_float(uv & 0xFFFF0000u);
                fh[f][j] = (short)(uv >> 16);
                fl[f][j] = (short)(__float_as_uint(lo) >> 16);
            }
        }
        short8 ah0, al0, ah1, al1;
#pragma unroll
        for (int j = 0; j < 8; ++j) {
            float v0 = As[lg * 8 + j][wave * 32 + lm];
            float v1 = As[lg * 8 + j][wave * 32 + 16 + lm];
            unsigned u0 = __float_as_uint(v0), u1 = __float_as_uint(v1);
            float l0 = v0 - __uint_as_float(u0 & 0xFFFF0000u);
            float l1 = v1 - __uint_as_float(u1 & 0xFFFF0000u);
            ah0[j] = (short)(u0 >> 16);
            al0[j] = (short)(__float_as_uint(l0) >> 16);
            ah1[j] = (short)(u1 >> 16);
            al1[j] = (short)(__float_as_uint(l1) >> 16);
        }

#pragma unroll
        for (int tj = 0; tj < 8; ++tj) {
            acc[tj]     = __builtin_amdgcn_mfma_f32_16x16x32_bf16(al0, fh[tj], acc[tj], 0, 0, 0);
            acc[tj]     = __builtin_amdgcn_mfma_f32_16x16x32_bf16(ah0, fl[tj], acc[tj], 0, 0, 0);
            acc[tj]     = __builtin_amdgcn_mfma_f32_16x16x32_bf16(ah0, fh[tj], acc[tj], 0, 0, 0);
            acc[8 + tj] = __builtin_amdgcn_mfma_f32_16x16x32_bf16(al1, fh[tj], acc[8 + tj], 0, 0, 0);
            acc[8 + tj] = __builtin_amdgcn_mfma_f32_16x16x32_bf16(ah1, fl[tj], acc[8 + tj], 0, 0, 0);
            acc[8 + tj] = __builtin_amdgcn_mfma_f32_16x16x32_bf16(ah1, fh[tj], acc[8 + tj], 0, 0, 0);
        }
    }

#pragma unroll
    for (int j = 0; j < 4; ++j) atomicAdd(&s_lds[(t & 31) * 4 + j], s_part[j]);
    __syncthreads();
    if (t < 128) atomicAdd(ws + WS_COLSA + (blockIdx.x & 7) * 128 + t, s_lds[t]);

    float* Gs = Gpart + (size_t)blockIdx.x * 16384;
#pragma unroll
    for (int a2 = 0; a2 < 2; ++a2) {
#pragma unroll
        for (int tj = 0; tj < 8; ++tj) {
#pragma unroll
            for (int g = 0; g < 4; ++g) {
                int gi = (2 * wave + a2) * 16 + lg * 4 + g;
                int gj = tj * 16 + lm;
                Gs[gi * 128 + gj] = acc[a2 * 8 + tj][g];
            }
        }
    }
}

// K1b: reduce GRAM_BLOCKS partials -> G final in ws
__global__ __launch_bounds__(256) void k1b_sumG(const float* __restrict__ Gpart,
                                                float* __restrict__ ws)
{
    int i = blockIdx.x * 256 + threadIdx.x;   // 0..16383
    float v = 0.f;
#pragma unroll 8
    for (int s = 0; s < GRAM_BLOCKS; ++s) v += Gpart[(size_t)s * 16384 + i];
    ws[WS_GF + i] = v;
}

// K2: per-column BN stats from Gram + fused W'-pack (W' = W*scale).
__global__ __launch_bounds__(128) void k2_finalize(
    const float* __restrict__ W, const float* __restrict__ gamma,
    const float* __restrict__ beta, float* __restrict__ ws,
    unsigned short* __restrict__ Whi, unsigned short* __restrict__ Wlo, int Brows)
{
    __shared__ float wcol[128];
    __shared__ float red[4];
    __shared__ float sres;
    const int t = threadIdx.x, n = blockIdx.x;
    wcol[t] = W[(size_t)t * UNITS + n];
    __syncthreads();
    const float* GF = ws + WS_GF;
    float q = 0.f;
#pragma unroll 8
    for (int i = 0; i < 128; ++i) q += GF[i * 128 + t] * wcol[i];
    q *= wcol[t];
    float csa = 0.f;
#pragma unroll
    for (int sl = 0; sl < 8; ++sl) csa += ws[WS_COLSA + sl * 128 + t];
    float mp = csa * wcol[t];
#pragma unroll
    for (int off = 32; off; off >>= 1) {
        q  += __shfl_xor(q, off, 64);
        mp += __shfl_xor(mp, off, 64);
    }
    if ((t & 63) == 0) { red[(t >> 6) * 2] = q; red[(t >> 6) * 2 + 1] = mp; }
    __syncthreads();
    if (t == 0) {
        float sumsq = red[0] + red[2], ssum = red[1] + red[3];
        float invB = 1.0f / (float)Brows;
        float mean = ssum * invB;
        float var  = sumsq * invB - mean * mean;
        float rstd = rsqrtf(var + 1e-3f);
        float sc   = rstd * gamma[n];
        ws[WS_SCALE + n] = sc;
        ws[WS_SHIFT + n] = beta[n] - mean * sc;
        sres = sc;
    }
    __syncthreads();
    float v = wcol[t] * sres;
    int c = t >> 5, j = t & 7, lane = ((t >> 3) & 3) * 16 + (n & 15), t8 = n >> 4;
    int dst = (((c * 32 + t8) * 64 + lane) << 3) + j;
    unsigned short hi = f2bf(v);
    Whi[dst] = hi;
    Wlo[dst] = f2bf(v - bf2f(hi));
}

// K3: swapped-operand fused kernel. 256 thr = 4 waves x 16 rows; W LDS-staged
// (global_load_lds, dbuf); 2 blocks/CU phase overlap. Sparsemax tail via
// PER-LANE LDS candidate compaction (conflict-free layout, no atomics):
// first Newton pass fused with compaction, iters 2+ scan ~2 candidates/lane,
// entropy from candidates only (exact).
__global__ __launch_bounds__(256, 2) void k3_fused(
    const float* __restrict__ A, const unsigned short* __restrict__ Whi,
    const unsigned short* __restrict__ Wlo, const float* __restrict__ prior,
    float* __restrict__ out, float* __restrict__ ws)
{
    __shared__ short8 wb[2][2][16][64];   // 64 KB; aliased as cand[] after GEMM
    float* cand = (float*)wb;             // cand[slot*256 + tid], bank = tid%32

    const int tid = threadIdx.x;
    const int wave = tid >> 6, lane = tid & 63, lg = lane >> 4, lm = lane & 15;
    const int r0 = blockIdx.x * 64 + wave * 16;

    // A fragments (B-operand of the swapped mfma): row = r0+lm, k = lg*8+j
    short8 ahi[4], alo[4];
    const float* arow = A + (size_t)(r0 + lm) * DIN + lg * 8;
#pragma unroll
    for (int c = 0; c < 4; ++c) {
        float4 f0 = *(const float4*)(arow + c * 32);
        float4 f1 = *(const float4*)(arow + c * 32 + 4);
        float fv[8] = {f0.x, f0.y, f0.z, f0.w, f1.x, f1.y, f1.z, f1.w};
#pragma unroll
        for (int j = 0; j < 8; ++j) {
            unsigned uv = __float_as_uint(fv[j]);
            float lo = fv[j] - __uint_as_float(uv & 0xFFFF0000u);
            ahi[c][j] = (short)(uv >> 16);
            alo[c][j] = (short)(__float_as_uint(lo) >> 16);
        }
    }

#define K3_STAGE(s, buf)                                                          \
    {                                                                             \
        const int H_ = (s) >> 2, c_ = (s) & 3;                                    \
        const unsigned short* srcH_ = Whi + (size_t)((c_ * 32 + H_ * 16) * 64) * 8;\
        const unsigned short* srcL_ = Wlo + (size_t)((c_ * 32 + H_ * 16) * 64) * 8;\
        _Pragma("unroll")                                                         \
        for (int i_ = 0; i_ < 8; ++i_) {                                          \
            int q_ = i_ * 256 + tid;                                              \
            const unsigned short* src_ = (q_ >> 10) ? srcL_ + (size_t)(q_ & 1023) * 8 \
                                                    : srcH_ + (size_t)(q_ & 1023) * 8; \
            __builtin_amdgcn_global_load_lds(                                     \
                (const __attribute__((address_space(1))) void*)src_,              \
                (__attribute__((address_space(3))) void*)&wb[buf][q_ >> 10][(q_ >> 6) & 15][q_ & 63], \
                16, 0, 0);                                                        \
        }                                                                         \
    }

    // acc[t][g] = X_bn[r=lm][n = t*16 + lg*4 + g]; init = shift[n]
    f32x4 acc[32];
#pragma unroll
    for (int t = 0; t < 32; ++t)
        acc[t] = *(const f32x4*)(ws + WS_SHIFT + t * 16 + lg * 4);

    K3_STAGE(0, 0);
    asm volatile("s_waitcnt vmcnt(0)" ::: "memory");
    __syncthreads();

    float m = -3.4e38f;   // row max, folded per col-half
#pragma unroll
    for (int H = 0; H < 2; ++H) {
#pragma unroll
        for (int c = 0; c < 4; ++c) {
            const int s = H * 4 + c;
            if (s == 0) { K3_STAGE(1, 1); }
            else if (s == 1) { K3_STAGE(2, 0); }
            else if (s == 2) { K3_STAGE(3, 1); }
            else if (s == 3) { K3_STAGE(4, 0); }
            else if (s == 4) { K3_STAGE(5, 1); }
            else if (s == 5) { K3_STAGE(6, 0); }
            else if (s == 6) { K3_STAGE(7, 1); }
            const int buf = s & 1;
#pragma unroll
            for (int t = 0; t < 16; ++t) {
                short8 h = wb[buf][0][t][lane];
                short8 l = wb[buf][1][t][lane];
                acc[H * 16 + t] = __builtin_amdgcn_mfma_f32_16x16x32_bf16(h, alo[c], acc[H * 16 + t], 0, 0, 0);
                acc[H * 16 + t] = __builtin_amdgcn_mfma_f32_16x16x32_bf16(l, ahi[c], acc[H * 16 + t], 0, 0, 0);
                acc[H * 16 + t] = __builtin_amdgcn_mfma_f32_16x16x32_bf16(h, ahi[c], acc[H * 16 + t], 0, 0, 0);
            }
            if (s < 7) {
                asm volatile("s_waitcnt vmcnt(0)" ::: "memory");
                __syncthreads();
            }
        }
        // prior-mul + max for this col-half (overlaps next half's prefetch)
        const float* prow = prior + (size_t)(r0 + lm) * UNITS + lg * 4;
#pragma unroll
        for (int t = 0; t < 16; ++t) {
            float4 p = *(const float4*)(prow + (H * 16 + t) * 16);
            acc[H * 16 + t][0] *= p.x;
            acc[H * 16 + t][1] *= p.y;
            acc[H * 16 + t][2] *= p.z;
            acc[H * 16 + t][3] *= p.w;
            m = fmaxf(m, fmaxf(fmaxf(acc[H * 16 + t][0], acc[H * 16 + t][1]),
                               fmaxf(acc[H * 16 + t][2], acc[H * 16 + t][3])));
        }
    }

    // combine the row's 4 lanes (xor 16, 32)
    m = fmaxf(m, __shfl_xor(m, 16, 64));
    m = fmaxf(m, __shfl_xor(m, 32, 64));

    // ---- pass 1 (fused): S,K at tau0 = m-1 + per-lane candidate compaction ----
    __syncthreads();   // all waves done with wb before cand aliases it
    const float tau0 = m - 1.0f;
    float S = 0.f, K = 0.f;
    int myc = 0;
#pragma unroll
    for (int t = 0; t < 32; ++t) {
#pragma unroll
        for (int g = 0; g < 4; ++g) {
            float v = acc[t][g];
            if (v > tau0) {
                S += v; K += 1.f;
                if (myc < NCAP) cand[myc * 256 + tid] = v;
                ++myc;
            }
        }
    }
    unsigned long long ovf = __ballot(myc > NCAP);

    S += __shfl_xor(S, 16, 64); S += __shfl_xor(S, 32, 64);
    K += __shfl_xor(K, 16, 64); K += __shfl_xor(K, 32, 64);
    float tau = tau0;
    {
        float nt = (S - 1.0f) / K;
        if (nt > tau) tau = nt;
    }

    float ent = 0.f;
    if (ovf == 0ull) {
        // ---- iters 2+: scan only this lane's candidates (~2) ----
        for (int it = 0; it < 23; ++it) {
            float S2 = 0.f, K2 = 0.f;
            for (int i = 0; i < myc; ++i) {
                float v = cand[i * 256 + tid];
                if (v > tau) { S2 += v; K2 += 1.f; }
            }
            S2 += __shfl_xor(S2, 16, 64); S2 += __shfl_xor(S2, 32, 64);
            K2 += __shfl_xor(K2, 16, 64); K2 += __shfl_xor(K2, 32, 64);
            float nt = (S2 - 1.0f) / K2;
            int chg = (nt > tau);
            if (chg) tau = nt;
            if (__ballot(chg) == 0ull) break;
        }
        // entropy from candidates only (non-candidates have v=0 -> exact 0 term)
        for (int i = 0; i < myc; ++i) {
            float v = cand[i * 256 + tid] - tau;
            if (v > 0.f) ent -= v * __logf(v + 1e-15f);
        }
    } else {
        // fallback: verified full-scan ballot Newton + full entropy
        for (int it = 0; it < 23; ++it) {
            float S2 = 0.f, K2 = 0.f;
#pragma unroll
            for (int t = 0; t < 32; ++t) {
#pragma unroll
                for (int g = 0; g < 4; ++g) {
                    float v = acc[t][g];
                    if (v > tau) { S2 += v; K2 += 1.f; }
                }
            }
            S2 += __shfl_xor(S2, 16, 64); S2 += __shfl_xor(S2, 32, 64);
            K2 += __shfl_xor(K2, 16, 64); K2 += __shfl_xor(K2, 32, 64);
            float nt = (S2 - 1.0f) / K2;
            int chg = (nt > tau);
            if (chg) tau = nt;
            if (__ballot(chg) == 0ull) break;
        }
#pragma unroll
        for (int t = 0; t < 32; ++t) {
#pragma unroll
            for (int g = 0; g < 4; ++g) {
                float v = fmaxf(acc[t][g] - tau, 0.f);
                if (v > 0.f) ent -= v * __logf(v + 1e-15f);
            }
        }
    }

    // ---- mask write (no logs) ----
    float* orow = out + (size_t)(r0 + lm) * UNITS + lg * 4;
#pragma unroll
    for (int t = 0; t < 32; ++t) {
        float4 o;
        o.x = fmaxf(acc[t][0] - tau, 0.f);
        o.y = fmaxf(acc[t][1] - tau, 0.f);
        o.z = fmaxf(acc[t][2] - tau, 0.f);
        o.w = fmaxf(acc[t][3] - tau, 0.f);
        *(float4*)(orow + t * 16) = o;
    }

#pragma unroll
    for (int off = 32; off; off >>= 1) ent += __shfl_xor(ent, off, 64);
    if (lane == 0)
        atomicAdd(&ws[WS_ESLOT + ((blockIdx.x * 4 + wave) & (N_ESLOT - 1))], ent);
#undef K3_STAGE
}

// K4: reduce entropy slots -> scalar loss
__global__ void k4_loss(const float* __restrict__ ws, float* __restrict__ out_loss,
                        int Brows)
{
    __shared__ float sh[512];
    int t = threadIdx.x;
    sh[t] = ws[WS_ESLOT + t];
    __syncthreads();
    for (int s = 256; s > 0; s >>= 1) {
        if (t < s) sh[t] += sh[t + s];
        __syncthreads();
    }
    if (t == 0) out_loss[0] = 1e-3f * (sh[0] / (float)Brows) * (1.0f / 3.0f);
}

extern "C" void kernel_launch(void* const* d_in, const int* in_sizes, int n_in,
                              void* d_out, int out_size, void* d_ws, size_t ws_size,
                              hipStream_t stream)
{
    const float* inputs = (const float*)d_in[0];
    const float* prior  = (const float*)d_in[1];
    const float* Wm     = (const float*)d_in[2];
    const float* gamma  = (const float*)d_in[3];
    const float* beta   = (const float*)d_in[4];
    float* out = (float*)d_out;
    float* ws  = (float*)d_ws;
    unsigned short* Whi = (unsigned short*)(ws + WS_WHI);
    unsigned short* Wlo = (unsigned short*)(ws + WS_WLO);
    const int Brows = in_sizes[1] / UNITS;   // 131072

    // d_out doubles as Gram-partial scratch (33.5 MB) before k3 overwrites it.
    float* Gpart = out;

    hipMemsetAsync(ws, 0, WS_ZERO_FLOATS * sizeof(float), stream);

    k1a_gram<<<GRAM_BLOCKS, 256, 0, stream>>>(inputs, Gpart, ws, Brows);
    k1b_sumG<<<64, 256, 0, stream>>>(Gpart, ws);
    k2_finalize<<<UNITS, 128, 0, stream>>>(Wm, gamma, beta, ws, Whi, Wlo, Brows);
    k3_fused<<<Brows / 64, 256, 0, stream>>>(inputs, Whi, Wlo, prior, out, ws);
    k4_loss<<<1, N_ESLOT, 0, stream>>>(ws, out + (size_t)Brows * UNITS, Brows);
}